// Round 10
// baseline (580.400 us; speedup 1.0000x reference)
//
#include <hip/hip_runtime.h>
#include <cmath>

// ---- problem constants ----
// B=2, d=128, C_bev=256, C_rv=64, Hrv=32, Wrv=1024 (Nq=32768), Hb=Wb=128 (HW=16384)
// heads=8, points=6, hd=16
#define HWB   16384
#define NQTOT 65536      // B * Nq

// ---- workspace layout (float offsets) ----
#define WS_W2T   0UL        // [256][128]  (vp_W @ Wv)^T  c-major
#define WS_BIAS2 32768UL    // [128]       vp_W@bv + vp_b
#define WS_PX    32896UL    // [128][128]  x-major: PX[x][dout]
#define WS_PY    49280UL    // [128][128]
#define WS_WQ2   65664UL    // [128][272]  [Wq^T | Wq^T@SAWT]  c-major
#define WS_OPWT  100480UL   // [128][128]
#define WS_F1T   116864UL
#define WS_F2T   133248UL
#define WS_WOT   149632UL   // [128][64]
#define WS_B3    157824UL   // [272]  [bq | bq@SAWT + sab]
#define WS_Q     158096UL   // [65536][128]   q (live until opln residual)
#define WS_V     8546704UL  // [2*16384][128]
#define WS_SA    12741008UL // [65536][144]   sa ; later region reused as y1
#define WS_Y1    12741008UL // [65536][128]
#define WS_MS    22178192UL // [65536][128]   msda out ; later FFN hidden t
#define WS_T     22178192UL
// total = 30,566,800 floats = 122.27 MB

#define FMA4(A, S, W) { A.x += (S)*(W).x; A.y += (S)*(W).y; A.z += (S)*(W).z; A.w += (S)*(W).w; }
#define ADD4(A, B4)   { A.x += (B4).x;    A.y += (B4).y;    A.z += (B4).z;    A.w += (B4).w;    }

// stage 32 rows of a [*][128] row-major matrix into col-major xt[128][36]
#define STAGE_T32(SRC) { \
    _Pragma("unroll") \
    for (int i = 0; i < 4; ++i) { \
        int f4 = i * 256 + t; int r = f4 >> 5, c4 = (f4 & 31) << 2; \
        float4 v = *(const float4*)&(SRC)[(size_t)r * 128 + c4]; \
        xt[(c4+0)*36 + r] = v.x; xt[(c4+1)*36 + r] = v.y; \
        xt[(c4+2)*36 + r] = v.z; xt[(c4+3)*36 + r] = v.w; \
    } \
    __syncthreads(); }

// ============ prep: fused/transposed weight tables ============
__global__ __launch_bounds__(256) void prep_k(
    const float* __restrict__ vpW, const float* __restrict__ Wv,
    const float* __restrict__ bv,  const float* __restrict__ vpb,
    const float* __restrict__ Wq,  const float* __restrict__ soW,
    const float* __restrict__ awW, const float* __restrict__ opW,
    const float* __restrict__ f1W, const float* __restrict__ f2W,
    const float* __restrict__ Wo,  const float* __restrict__ sob,
    const float* __restrict__ awb, const float* __restrict__ bq,
    float* __restrict__ ws)
{
    int idx = blockIdx.x * 256 + threadIdx.x;
    const float NEG = -0.14391156831212787f;   // -ln(10000)/64
    if (idx < 32768) {                         // W2T[c][dout] = sum_k vpW[dout,k]*Wv[k,c]
        int c = idx >> 7, dd = idx & 127;
        float s = 0.f;
        for (int k = 0; k < 128; ++k) s += vpW[dd*128 + k] * Wv[k*256 + c];
        ws[WS_W2T + idx] = s;
        return;
    }
    idx -= 32768;
    if (idx < 128) {                           // bias2 = vpW@bv + vpb
        float s = vpb[idx];
        for (int k = 0; k < 128; ++k) s += vpW[idx*128 + k] * bv[k];
        ws[WS_BIAS2 + idx] = s;
        return;
    }
    idx -= 128;
    if (idx < 16384) {                         // PX[x][dout]
        int x = idx >> 7, dd = idx & 127;
        float fx = (float)x, s = 0.f;
        for (int i = 0; i < 32; ++i) {
            float dv = expf((float)(2*i) * NEG);
            float sv, cv; sincosf(fx * dv, &sv, &cv);
            s += vpW[dd*128 + 2*i] * sv + vpW[dd*128 + 2*i + 1] * cv;
        }
        ws[WS_PX + idx] = s;
        return;
    }
    idx -= 16384;
    if (idx < 16384) {                         // PY[y][dout]
        int y = idx >> 7, dd = idx & 127;
        float fy = (float)y, s = 0.f;
        for (int i = 0; i < 32; ++i) {
            float dv = expf((float)(2*i) * NEG);
            float sv, cv; sincosf(fy * dv, &sv, &cv);
            s += vpW[dd*128 + 64 + 2*i] * sv + vpW[dd*128 + 64 + 2*i + 1] * cv;
        }
        ws[WS_PY + idx] = s;
        return;
    }
    idx -= 16384;
    if (idx < 16384) {                         // WQ2 q-part: [c][j] = Wq[j][c]
        int c = idx >> 7, j = idx & 127;
        ws[WS_WQ2 + (size_t)c*272 + j] = Wq[j*128 + c];
        return;
    }
    idx -= 16384;
    if (idx < 18432) {                         // WQ2 sa-part: [c][128+jj] = sum_k Wq[k][c]*soaw[jj][k]
        int c = idx / 144, jj = idx % 144;
        const float* r = (jj < 96) ? (soW + jj*128) : (awW + (jj-96)*128);
        float s = 0.f;
        for (int k = 0; k < 128; k += 4) {
            float4 r4 = *(const float4*)&r[k];
            s += Wq[k*128 + c]       * r4.x + Wq[(k+1)*128 + c] * r4.y
               + Wq[(k+2)*128 + c]   * r4.z + Wq[(k+3)*128 + c] * r4.w;
        }
        ws[WS_WQ2 + (size_t)c*272 + 128 + jj] = s;
        return;
    }
    idx -= 18432;
    if (idx < 16384) { ws[WS_OPWT + idx] = opW[(idx & 127)*128 + (idx >> 7)]; return; }
    idx -= 16384;
    if (idx < 16384) { ws[WS_F1T  + idx] = f1W[(idx & 127)*128 + (idx >> 7)]; return; }
    idx -= 16384;
    if (idx < 16384) { ws[WS_F2T  + idx] = f2W[(idx & 127)*128 + (idx >> 7)]; return; }
    idx -= 16384;
    if (idx < 8192)  { ws[WS_WOT  + idx] = Wo [(idx & 63)*128 + (idx >> 6)]; return; }
    idx -= 8192;
    if (idx < 272) {                           // B3 = [bq | bq@SAWT + sab]
        if (idx < 128) { ws[WS_B3 + idx] = bq[idx]; return; }
        int jj = idx - 128;
        const float* r = (jj < 96) ? (soW + jj*128) : (awW + (jj-96)*128);
        float s = (jj < 96) ? sob[jj] : awb[jj-96];
        for (int k = 0; k < 128; ++k) s += bq[k] * r[k];
        ws[WS_B3 + idx] = s;
    }
}

// ============ value: v = W2T.bev + PX[x] + PY[y] + bias2  (K=256 GEMM tile) ============
__global__ __launch_bounds__(256) void value_k(const float* __restrict__ bev, float* __restrict__ ws)
{
    __shared__ __align__(16) float bt[256 * 32];   // [c][pos]
    int t = threadIdx.x, blk = blockIdx.x;
    int b = blk >> 9;                              // 512 tiles per batch
    int n0 = (blk & 511) << 5;
    const float* src = bev + (size_t)b * 256 * HWB + n0;
#pragma unroll
    for (int i = 0; i < 32; ++i) {
        int flat = i * 256 + t;
        bt[flat] = src[(size_t)(flat >> 5) * HWB + (flat & 31)];
    }
    __syncthreads();
    int p0 = (t >> 5) << 2, d0 = (t & 31) << 2;
    float4 a0 = {0,0,0,0}, a1 = a0, a2 = a0, a3 = a0;
    const float* WT = ws + WS_W2T;
    for (int c = 0; c < 256; ++c) {
        float4 xv = *(const float4*)&bt[c*32 + p0];
        float4 wv = *(const float4*)&WT[c*128 + d0];
        FMA4(a0, xv.x, wv); FMA4(a1, xv.y, wv); FMA4(a2, xv.z, wv); FMA4(a3, xv.w, wv);
    }
    const float* PX = ws + WS_PX; const float* PY = ws + WS_PY;
    float4 b2 = *(const float4*)&ws[WS_BIAS2 + d0];
    float* vout = ws + WS_V;
#define VSTORE(ACC, PI) { \
        int n = n0 + p0 + (PI); int x = n & 127, y = n >> 7; \
        float4 px = *(const float4*)&PX[x*128 + d0]; \
        float4 py = *(const float4*)&PY[y*128 + d0]; \
        ADD4(ACC, px); ADD4(ACC, py); ADD4(ACC, b2); \
        *(float4*)&vout[((size_t)b*HWB + n)*128 + d0] = ACC; }
    VSTORE(a0, 0) VSTORE(a1, 1) VSTORE(a2, 2) VSTORE(a3, 3)
#undef VSTORE
}

// ============ q,sa = rv^T @ WQ2 + B3  (64-position tile, 8 pos x 1 col-group/thread) ============
__global__ __launch_bounds__(256) void qsa_k(const float* __restrict__ rv, float* __restrict__ ws)
{
    __shared__ __align__(16) float sh[128 * 64];   // [c][pos]  32 KB
    int t = threadIdx.x, blk = blockIdx.x;
    int b = blk >> 9;                              // 512 tiles per batch
    int n0 = (blk & 511) << 6;
    const float* src = rv + (size_t)b * 128 * 32768 + n0;
#pragma unroll
    for (int i = 0; i < 32; ++i) {
        int flat = i * 256 + t;
        sh[flat] = src[(size_t)(flat >> 6) * 32768 + (flat & 63)];
    }
    __syncthreads();
    int pr = t >> 5;                               // 0..7 -> positions pr*8..pr*8+7
    int jc = t & 31;                               // col group (float4)
    bool hasC = (jc < 4);
    const float* W = ws + WS_WQ2;
    float4 z = {0,0,0,0};
    float4 qa0=z,qa1=z,qa2=z,qa3=z,qa4=z,qa5=z,qa6=z,qa7=z;   // q cols 4jc, 8 positions
    float4 sb0=z,sb1=z,sb2=z,sb3=z,sb4=z,sb5=z,sb6=z,sb7=z;   // sa cols 4jc
    float4 sc0=z,sc1=z,sc2=z,sc3=z,sc4=z,sc5=z,sc6=z,sc7=z;   // sa cols 128+4jc (jc<4)
    for (int c = 0; c < 128; ++c) {
        float4 x0 = *(const float4*)&sh[c*64 + pr*8];
        float4 x1 = *(const float4*)&sh[c*64 + pr*8 + 4];
        const float* wr = W + (size_t)c*272;
        float4 wA = *(const float4*)&wr[4*jc];
        float4 wB = *(const float4*)&wr[128 + 4*jc];
        FMA4(qa0, x0.x, wA); FMA4(qa1, x0.y, wA); FMA4(qa2, x0.z, wA); FMA4(qa3, x0.w, wA);
        FMA4(qa4, x1.x, wA); FMA4(qa5, x1.y, wA); FMA4(qa6, x1.z, wA); FMA4(qa7, x1.w, wA);
        FMA4(sb0, x0.x, wB); FMA4(sb1, x0.y, wB); FMA4(sb2, x0.z, wB); FMA4(sb3, x0.w, wB);
        FMA4(sb4, x1.x, wB); FMA4(sb5, x1.y, wB); FMA4(sb6, x1.z, wB); FMA4(sb7, x1.w, wB);
        if (hasC) {
            float4 wC = *(const float4*)&wr[256 + 4*jc];
            FMA4(sc0, x0.x, wC); FMA4(sc1, x0.y, wC); FMA4(sc2, x0.z, wC); FMA4(sc3, x0.w, wC);
            FMA4(sc4, x1.x, wC); FMA4(sc5, x1.y, wC); FMA4(sc6, x1.z, wC); FMA4(sc7, x1.w, wC);
        }
    }
    const float* B3 = ws + WS_B3;
    float4 bA = *(const float4*)&B3[4*jc];
    float4 bB = *(const float4*)&B3[128 + 4*jc];
    size_t row = (size_t)b * 32768 + n0 + pr*8;
    float* qout  = ws + WS_Q  + row * 128 + 4*jc;
    float* saout = ws + WS_SA + row * 144 + 4*jc;
    ADD4(qa0, bA); *(float4*)&qout[0*128] = qa0;
    ADD4(qa1, bA); *(float4*)&qout[1*128] = qa1;
    ADD4(qa2, bA); *(float4*)&qout[2*128] = qa2;
    ADD4(qa3, bA); *(float4*)&qout[3*128] = qa3;
    ADD4(qa4, bA); *(float4*)&qout[4*128] = qa4;
    ADD4(qa5, bA); *(float4*)&qout[5*128] = qa5;
    ADD4(qa6, bA); *(float4*)&qout[6*128] = qa6;
    ADD4(qa7, bA); *(float4*)&qout[7*128] = qa7;
    ADD4(sb0, bB); *(float4*)&saout[0*144] = sb0;
    ADD4(sb1, bB); *(float4*)&saout[1*144] = sb1;
    ADD4(sb2, bB); *(float4*)&saout[2*144] = sb2;
    ADD4(sb3, bB); *(float4*)&saout[3*144] = sb3;
    ADD4(sb4, bB); *(float4*)&saout[4*144] = sb4;
    ADD4(sb5, bB); *(float4*)&saout[5*144] = sb5;
    ADD4(sb6, bB); *(float4*)&saout[6*144] = sb6;
    ADD4(sb7, bB); *(float4*)&saout[7*144] = sb7;
    if (hasC) {
        float4 bC = *(const float4*)&B3[256 + 4*jc];
        ADD4(sc0, bC); *(float4*)&saout[0*144 + 128] = sc0;
        ADD4(sc1, bC); *(float4*)&saout[1*144 + 128] = sc1;
        ADD4(sc2, bC); *(float4*)&saout[2*144 + 128] = sc2;
        ADD4(sc3, bC); *(float4*)&saout[3*144 + 128] = sc3;
        ADD4(sc4, bC); *(float4*)&saout[4*144 + 128] = sc4;
        ADD4(sc5, bC); *(float4*)&saout[5*144 + 128] = sc5;
        ADD4(sc6, bC); *(float4*)&saout[6*144 + 128] = sc6;
        ADD4(sc7, bC); *(float4*)&saout[7*144 + 128] = sc7;
    }
}

// ============ sampling: float4 gathers, 4 lanes/head, 2 queries/wave ============
__global__ __launch_bounds__(256) void samp_k(const float* __restrict__ ref, float* __restrict__ ws)
{
    int t = threadIdx.x;
    int w = t >> 6, l = t & 63;
    int g = blockIdx.x * 8 + w * 2 + (l >> 5);     // query id, < 65536
    int b = g >> 15;
    const float* sa = ws + WS_SA + (size_t)g * 144;
    int hh = (l >> 2) & 7, s = l & 3;
    float lg[6]; float mx = -1e30f;
#pragma unroll
    for (int p = 0; p < 6; ++p) { lg[p] = sa[96 + hh*6 + p]; mx = fmaxf(mx, lg[p]); }
    float ssum = 0.f;
#pragma unroll
    for (int p = 0; p < 6; ++p) { lg[p] = expf(lg[p] - mx); ssum += lg[p]; }
    float inv = 1.f / ssum;
    float rx = ref[(size_t)g*2], ry = ref[(size_t)g*2 + 1];
    const float* vb = ws + WS_V + ((size_t)b * HWB) * 128 + hh*16 + s*4;
    float4 a = {0,0,0,0};
#pragma unroll
    for (int p = 0; p < 6; ++p) {
        float ox = sa[(hh*6 + p)*2], oy = sa[(hh*6 + p)*2 + 1];
        float xx = (rx + ox * 0.0078125f) * 128.f - 0.5f;   // (ref + off/W)*W - 0.5
        float yy = (ry + oy * 0.0078125f) * 128.f - 0.5f;
        float xf = floorf(xx), yf = floorf(yy);
        float lx = xx - xf, ly = yy - yf;
        int ix = (int)xf, iy = (int)yf;
        float4 c4 = {0,0,0,0};
#define CORNER(XI, YI, WW) { int xi = (XI), yi = (YI); \
        if (xi >= 0 && xi < 128 && yi >= 0 && yi < 128) { \
            const float4 gv = *(const float4*)(vb + (size_t)(yi*128 + xi)*128); \
            float wv = (WW); FMA4(c4, wv, gv); } }
        CORNER(ix,     iy,     (1.f-lx)*(1.f-ly));
        CORNER(ix + 1, iy,     lx*(1.f-ly));
        CORNER(ix,     iy + 1, (1.f-lx)*ly);
        CORNER(ix + 1, iy + 1, lx*ly);
#undef CORNER
        float aw = lg[p] * inv;
        FMA4(a, aw, c4);
    }
    *(float4*)(ws + WS_MS + (size_t)g*128 + hh*16 + s*4) = a;
}

// ============ op proj + residual(q) + LN1 -> y1  (32 rows, 4x4 per thread) ============
__global__ __launch_bounds__(256) void opln_k(const float* __restrict__ opb,
    const float* __restrict__ ln1g, const float* __restrict__ ln1b, float* __restrict__ ws)
{
    __shared__ __align__(16) float xt[128 * 36];
    int t = threadIdx.x;
    size_t row0 = (size_t)blockIdx.x * 32;
    const float* src = ws + WS_MS + row0 * 128;
    STAGE_T32(src)
    int d0 = (t & 31) << 2, rbase = (t >> 5) << 2;
    const float* WT = ws + WS_OPWT;
    float4 a0 = {0,0,0,0}, a1 = a0, a2 = a0, a3 = a0;
#pragma unroll 4
    for (int c = 0; c < 128; ++c) {
        float4 x = *(const float4*)&xt[c*36 + rbase];
        float4 w = *(const float4*)&WT[c*128 + d0];
        FMA4(a0, x.x, w); FMA4(a1, x.y, w); FMA4(a2, x.z, w); FMA4(a3, x.w, w);
    }
    float4 ob = *(const float4*)&opb[d0];
    float4 g4 = *(const float4*)&ln1g[d0];
    float4 b4 = *(const float4*)&ln1b[d0];
    float4 acc[4] = {a0, a1, a2, a3};
#pragma unroll
    for (int i = 0; i < 4; ++i) {
        size_t grow = row0 + rbase + i;
        float4 q4 = *(const float4*)&ws[WS_Q + grow*128 + d0];
        float4 A = acc[i];
        ADD4(A, q4); ADD4(A, ob);
        float sm = A.x + A.y + A.z + A.w;
        sm += __shfl_xor(sm,1); sm += __shfl_xor(sm,2); sm += __shfl_xor(sm,4);
        sm += __shfl_xor(sm,8); sm += __shfl_xor(sm,16);
        float mean = sm * 0.0078125f;
        A.x -= mean; A.y -= mean; A.z -= mean; A.w -= mean;
        float vv = A.x*A.x + A.y*A.y + A.z*A.z + A.w*A.w;
        vv += __shfl_xor(vv,1); vv += __shfl_xor(vv,2); vv += __shfl_xor(vv,4);
        vv += __shfl_xor(vv,8); vv += __shfl_xor(vv,16);
        float rstd = rsqrtf(vv * 0.0078125f + 1e-5f);
        float4 r4;
        r4.x = A.x*rstd*g4.x + b4.x; r4.y = A.y*rstd*g4.y + b4.y;
        r4.z = A.z*rstd*g4.z + b4.z; r4.w = A.w*rstd*g4.w + b4.w;
        *(float4*)&ws[WS_Y1 + grow*128 + d0] = r4;
    }
}

// ============ FFN hidden: t = gelu(y1 @ f1T + f1b)  (32 rows, 4x4 per thread) ============
__global__ __launch_bounds__(256) void f1_k(const float* __restrict__ f1b, float* __restrict__ ws)
{
    __shared__ __align__(16) float xt[128 * 36];
    int t = threadIdx.x;
    size_t row0 = (size_t)blockIdx.x * 32;
    const float* src = ws + WS_Y1 + row0 * 128;
    STAGE_T32(src)
    int d0 = (t & 31) << 2, rbase = (t >> 5) << 2;
    const float* WT = ws + WS_F1T;
    float4 a0 = {0,0,0,0}, a1 = a0, a2 = a0, a3 = a0;
#pragma unroll 4
    for (int c = 0; c < 128; ++c) {
        float4 x = *(const float4*)&xt[c*36 + rbase];
        float4 w = *(const float4*)&WT[c*128 + d0];
        FMA4(a0, x.x, w); FMA4(a1, x.y, w); FMA4(a2, x.z, w); FMA4(a3, x.w, w);
    }
    float4 bb = *(const float4*)&f1b[d0];
    float4 acc[4] = {a0, a1, a2, a3};
#pragma unroll
    for (int i = 0; i < 4; ++i) {
        float4 A = acc[i];
        ADD4(A, bb);
#define GELU(X) ((X) = 0.5f*(X)*(1.f + erff((X)*0.70710678118654752f)))
        GELU(A.x); GELU(A.y); GELU(A.z); GELU(A.w);
#undef GELU
        *(float4*)&ws[WS_T + (row0 + rbase + i)*128 + d0] = A;
    }
}

// ============ z = t @ f2T + f2b + y1 ; LN2 ; out = yf @ WoT + bo (fused, 32 rows) ============
__global__ __launch_bounds__(256) void f2lnout_k(const float* __restrict__ f2b,
    const float* __restrict__ ln2g, const float* __restrict__ ln2b,
    const float* __restrict__ bo, float* __restrict__ out, float* __restrict__ ws)
{
    __shared__ __align__(16) float xt[128 * 36];
    int t = threadIdx.x;
    size_t row0 = (size_t)blockIdx.x * 32;
    const float* src = ws + WS_T + row0 * 128;
    STAGE_T32(src)
    int d0 = (t & 31) << 2, rbase = (t >> 5) << 2;
    const float* WT = ws + WS_F2T;
    float4 a0 = {0,0,0,0}, a1 = a0, a2 = a0, a3 = a0;
#pragma unroll 4
    for (int c = 0; c < 128; ++c) {
        float4 x = *(const float4*)&xt[c*36 + rbase];
        float4 w = *(const float4*)&WT[c*128 + d0];
        FMA4(a0, x.x, w); FMA4(a1, x.y, w); FMA4(a2, x.z, w); FMA4(a3, x.w, w);
    }
    __syncthreads();                               // all f2 reads of xt done
    float4 fb = *(const float4*)&f2b[d0];
    float4 g4 = *(const float4*)&ln2g[d0];
    float4 b4 = *(const float4*)&ln2b[d0];
    float4 acc[4] = {a0, a1, a2, a3};
#pragma unroll
    for (int i = 0; i < 4; ++i) {
        size_t grow = row0 + rbase + i;
        float4 y4 = *(const float4*)&ws[WS_Y1 + grow*128 + d0];
        float4 A = acc[i];
        ADD4(A, y4); ADD4(A, fb);
        float sm = A.x + A.y + A.z + A.w;
        sm += __shfl_xor(sm,1); sm += __shfl_xor(sm,2); sm += __shfl_xor(sm,4);
        sm += __shfl_xor(sm,8); sm += __shfl_xor(sm,16);
        float mean = sm * 0.0078125f;
        A.x -= mean; A.y -= mean; A.z -= mean; A.w -= mean;
        float vv = A.x*A.x + A.y*A.y + A.z*A.z + A.w*A.w;
        vv += __shfl_xor(vv,1); vv += __shfl_xor(vv,2); vv += __shfl_xor(vv,4);
        vv += __shfl_xor(vv,8); vv += __shfl_xor(vv,16);
        float rstd = rsqrtf(vv * 0.0078125f + 1e-5f);
        int rloc = rbase + i;
        xt[(d0+0)*36 + rloc] = A.x*rstd*g4.x + b4.x;
        xt[(d0+1)*36 + rloc] = A.y*rstd*g4.y + b4.y;
        xt[(d0+2)*36 + rloc] = A.z*rstd*g4.z + b4.z;
        xt[(d0+3)*36 + rloc] = A.w*rstd*g4.w + b4.w;
    }
    __syncthreads();
    int rr = (t >> 4) << 1;                        // 0..30
    int j0 = (t & 15) << 2;                        // 0..60
    const float* WO = ws + WS_WOT;
    float4 O0 = {0,0,0,0}, O1 = O0;
#pragma unroll 4
    for (int c = 0; c < 128; ++c) {
        float x0 = xt[c*36 + rr];
        float x1 = xt[c*36 + rr + 1];
        float4 w = *(const float4*)&WO[c*64 + j0];
        FMA4(O0, x0, w); FMA4(O1, x1, w);
    }
    float4 bb = *(const float4*)&bo[j0];
    ADD4(O0, bb); ADD4(O1, bb);
    *(float4*)&out[(row0 + rr)*64 + j0]     = O0;
    *(float4*)&out[(row0 + rr + 1)*64 + j0] = O1;
}

extern "C" void kernel_launch(void* const* d_in, const int* in_sizes, int n_in,
                              void* d_out, int out_size, void* d_ws, size_t ws_size,
                              hipStream_t stream) {
    const float* rv   = (const float*)d_in[0];
    const float* bev  = (const float*)d_in[1];
    const float* ref  = (const float*)d_in[2];
    const float* Wq   = (const float*)d_in[3];
    const float* bq   = (const float*)d_in[4];
    const float* Wv   = (const float*)d_in[5];
    const float* bv   = (const float*)d_in[6];
    const float* soW  = (const float*)d_in[7];
    const float* sob  = (const float*)d_in[8];
    const float* awW  = (const float*)d_in[9];
    const float* awb  = (const float*)d_in[10];
    const float* vpW  = (const float*)d_in[11];
    const float* vpb  = (const float*)d_in[12];
    const float* opW  = (const float*)d_in[13];
    const float* opb  = (const float*)d_in[14];
    const float* ln1g = (const float*)d_in[15];
    const float* ln1b = (const float*)d_in[16];
    const float* f1W  = (const float*)d_in[17];
    const float* f1b  = (const float*)d_in[18];
    const float* f2W  = (const float*)d_in[19];
    const float* f2b  = (const float*)d_in[20];
    const float* ln2g = (const float*)d_in[21];
    const float* ln2b = (const float*)d_in[22];
    const float* Wo   = (const float*)d_in[23];
    const float* bo   = (const float*)d_in[24];
    float* ws  = (float*)d_ws;
    float* out = (float*)d_out;

    prep_k   <<<618,  256, 0, stream>>>(vpW, Wv, bv, vpb, Wq, soW, awW, opW, f1W, f2W, Wo, sob, awb, bq, ws);
    value_k  <<<1024, 256, 0, stream>>>(bev, ws);
    qsa_k    <<<1024, 256, 0, stream>>>(rv, ws);
    samp_k   <<<8192, 256, 0, stream>>>(ref, ws);
    opln_k   <<<2048, 256, 0, stream>>>(opb, ln1g, ln1b, ws);
    f1_k     <<<2048, 256, 0, stream>>>(f1b, ws);
    f2lnout_k<<<2048, 256, 0, stream>>>(f2b, ln2g, ln2b, bo, out, ws);
}